// Round 9
// baseline (655.859 us; speedup 1.0000x reference)
//
#include <hip/hip_runtime.h>
#include <math.h>

#define NN 100000
#define NE 1600000
#define SLOTS 48           // fixed csr stride; P(deg>=48) ~ 6e-11 per node
#define NODES_PER_BUCKET 12500   // 8 buckets x 12500 = NN
#define QUADS (NE / 4)     // 400000
#define CSEG 128           // count-fill segments per bucket (1024 blocks total)
#define QPS2 ((QUADS + CSEG - 1) / CSEG)  // 3125
#define XCAST_T (NN * 32)            // 3,200,000 xcast threads
#define PREP_T (XCAST_T + 16384 + 128)
#define PREP_B ((PREP_T + 255) / 256)    // 12565
#define FRONT_B (1024 + PREP_B)

// bf16 <-> f32 helpers (bf16 stored as raw ushort; value<<16 == f32 bits)
__device__ __forceinline__ float bf2f(unsigned int u) {
    union { unsigned int u; float f; } c; c.u = u << 16; return c.f;
}
__device__ __forceinline__ unsigned short f2bf(float f) {
    union { float f; unsigned int u; } c; c.f = f;
    unsigned int x = c.u;
    return (unsigned short)((x + 0x7fffu + ((x >> 16) & 1u)) >> 16); // RNE
}

// ---------- k_front: CSR build (1024 blocks, dispatched first) + indep prep ----------
// R8-proven: count portion is atomic-rate bound, 1024 blocks sustain it while the
// prep (xq = bf16(x), W2c = W1@[Wmu|Wls], bw = b1@[Wmu|Wls]) fills freed capacity.
__global__ __launch_bounds__(256) void k_front(const int* __restrict__ ei,
        int* __restrict__ cnt, int* __restrict__ csr48,
        const float* __restrict__ x, unsigned short* __restrict__ xq,
        const float* __restrict__ W1, const float* __restrict__ Wmu,
        const float* __restrict__ Wls, const float* __restrict__ b1,
        unsigned short* __restrict__ W2c, float* __restrict__ bw) {
    int b = blockIdx.x;
    if (b < 1024) {
        int bucket = b & 7;
        int seg = b >> 3;                // 0..127
        int lo = bucket * NODES_PER_BUCKET, hi = lo + NODES_PER_BUCKET;
        int q1 = min((seg + 1) * QPS2, QUADS);
        for (int q = seg * QPS2 + (int)threadIdx.x; q < q1; q += 256) {
            int e0 = q * 4;
            int4 s = *(const int4*)(ei + e0);
            int4 d = *(const int4*)(ei + NE + e0);
            int r;
            if (d.x >= lo && d.x < hi) { r = atomicAdd(&cnt[d.x], 1); if (r < SLOTS) csr48[d.x * SLOTS + r] = s.x; }
            if (d.y >= lo && d.y < hi) { r = atomicAdd(&cnt[d.y], 1); if (r < SLOTS) csr48[d.y * SLOTS + r] = s.y; }
            if (d.z >= lo && d.z < hi) { r = atomicAdd(&cnt[d.z], 1); if (r < SLOTS) csr48[d.z * SLOTS + r] = s.z; }
            if (d.w >= lo && d.w < hi) { r = atomicAdd(&cnt[d.w], 1); if (r < SLOTS) csr48[d.w * SLOTS + r] = s.w; }
        }
    } else {
        int idx = (b - 1024) * 256 + (int)threadIdx.x;
        if (idx < XCAST_T) {
            int node = idx >> 5, c = (idx & 31) << 2;
            float4 v = *(const float4*)(x + (size_t)node * 128 + c);
            uint2 st;
            st.x = ((unsigned int)f2bf(v.y) << 16) | f2bf(v.x);
            st.y = ((unsigned int)f2bf(v.w) << 16) | f2bf(v.z);
            *(uint2*)(xq + (size_t)node * 128 + c) = st;
        } else if (idx < XCAST_T + 16384) {
            int j = idx - XCAST_T;
            int k = j >> 7, n = j & 127;        // k = input feat (K dim), n = out col
            const float* Wx = (n < 64) ? (Wmu + n) : (Wls + (n - 64));  // col base, stride 64
            float s = 0.f;
#pragma unroll 8
            for (int m = 0; m < 128; ++m) s += W1[k * 128 + m] * Wx[(size_t)m * 64];
            W2c[n * 128 + k] = f2bf(s);
        } else if (idx < PREP_T) {
            int n = idx - XCAST_T - 16384;
            const float* Wx = (n < 64) ? (Wmu + n) : (Wls + (n - 64));
            float s = 0.f;
            for (int m = 0; m < 128; ++m) s += b1[m] * Wx[(size_t)m * 64];
            bw[n] = s;
        }
    }
}

// -------- gather1: t1 = bf16(dn^2 * (dn*x_n + sum_s d_s*xq_s)); avec = dn*(dn+sum d_s) --------
__global__ __launch_bounds__(256) void k_gather1(
    const unsigned short* __restrict__ tab, const int* __restrict__ cnt,
    const int* __restrict__ csr48,
    unsigned short* __restrict__ yout, float* __restrict__ avec) {
    int node = blockIdx.x * 4 + (threadIdx.x >> 6);   // NN % 4 == 0
    int lane = threadIdx.x & 63;
    int q = lane >> 4, l16 = lane & 15;
    int deg = __builtin_amdgcn_readfirstlane(cnt[node]);
    float dn = rsqrtf((float)(deg + 1));              // raw degree (+self)
    if (deg > SLOTS) deg = SLOTS;
    float a[8] = {0.f, 0.f, 0.f, 0.f, 0.f, 0.f, 0.f, 0.f};
    float asum = 0.f;
    if (q == 0) {  // self term, scaled by dn
        uint4 p = *(const uint4*)(tab + (size_t)node * 128 + l16 * 8);
        a[0] = dn * bf2f(p.x & 0xffffu); a[1] = dn * bf2f(p.x >> 16);
        a[2] = dn * bf2f(p.y & 0xffffu); a[3] = dn * bf2f(p.y >> 16);
        a[4] = dn * bf2f(p.z & 0xffffu); a[5] = dn * bf2f(p.z >> 16);
        a[6] = dn * bf2f(p.w & 0xffffu); a[7] = dn * bf2f(p.w >> 16);
    }
    int base = node * SLOTS;
    int t = q;
    while (t + 4 < deg) {   // 2 edges per quarter in flight (8/wave)
        int s0 = csr48[base + t];
        int s1 = csr48[base + t + 4];
        float d0 = rsqrtf((float)(cnt[s0] + 1));
        float d1 = rsqrtf((float)(cnt[s1] + 1));
        uint4 r0 = *(const uint4*)(tab + (size_t)s0 * 128 + l16 * 8);
        uint4 r1 = *(const uint4*)(tab + (size_t)s1 * 128 + l16 * 8);
        asum += d0 + d1;
        a[0] += d0 * bf2f(r0.x & 0xffffu) + d1 * bf2f(r1.x & 0xffffu);
        a[1] += d0 * bf2f(r0.x >> 16)     + d1 * bf2f(r1.x >> 16);
        a[2] += d0 * bf2f(r0.y & 0xffffu) + d1 * bf2f(r1.y & 0xffffu);
        a[3] += d0 * bf2f(r0.y >> 16)     + d1 * bf2f(r1.y >> 16);
        a[4] += d0 * bf2f(r0.z & 0xffffu) + d1 * bf2f(r1.z & 0xffffu);
        a[5] += d0 * bf2f(r0.z >> 16)     + d1 * bf2f(r1.z >> 16);
        a[6] += d0 * bf2f(r0.w & 0xffffu) + d1 * bf2f(r1.w & 0xffffu);
        a[7] += d0 * bf2f(r0.w >> 16)     + d1 * bf2f(r1.w >> 16);
        t += 8;
    }
    while (t < deg) {
        int s = csr48[base + t];
        float ds = rsqrtf((float)(cnt[s] + 1));
        uint4 r = *(const uint4*)(tab + (size_t)s * 128 + l16 * 8);
        asum += ds;
        a[0] += ds * bf2f(r.x & 0xffffu); a[1] += ds * bf2f(r.x >> 16);
        a[2] += ds * bf2f(r.y & 0xffffu); a[3] += ds * bf2f(r.y >> 16);
        a[4] += ds * bf2f(r.z & 0xffffu); a[5] += ds * bf2f(r.z >> 16);
        a[6] += ds * bf2f(r.w & 0xffffu); a[7] += ds * bf2f(r.w >> 16);
        t += 4;
    }
#pragma unroll
    for (int j = 0; j < 8; ++j) {
        a[j] += __shfl_xor(a[j], 16);
        a[j] += __shfl_xor(a[j], 32);
    }
    asum += __shfl_xor(asum, 16);
    asum += __shfl_xor(asum, 32);
    if (q == 0) {
        float d2 = dn * dn;      // t1 = dn * g1: pre-scales the gather2 source
        uint4 st;
        st.x = ((unsigned int)f2bf(a[1] * d2) << 16) | f2bf(a[0] * d2);
        st.y = ((unsigned int)f2bf(a[3] * d2) << 16) | f2bf(a[2] * d2);
        st.z = ((unsigned int)f2bf(a[5] * d2) << 16) | f2bf(a[4] * d2);
        st.w = ((unsigned int)f2bf(a[7] * d2) << 16) | f2bf(a[6] * d2);
        *(uint4*)(yout + (size_t)node * 128 + l16 * 8) = st;
        if (l16 == 0) avec[node] = dn * (asum + dn);   // a = G*1
    }
}

// ------- gather2C: g2 = dn * sum t1[nbr] (kept in LDS, f32), then fused VALU GEMM + epilogue ----
// R4 lesson inverted: fuse the tiny GEMM (3.3 GFLOP ~ 21us VALU chip-wide) INTO the
// latency-bound 25000-block gather grid — the dot products hide under load stalls.
// Saves: gemmC dispatch + gap, 25.6MB g2 write + 25.6MB re-read.
__global__ __launch_bounds__(256) void k_gather2C(
    const unsigned short* __restrict__ tab,  // t1 [NN][128] bf16 (pre-scaled by src dn)
    const int* __restrict__ cnt, const int* __restrict__ csr48,
    const unsigned short* __restrict__ W2c,  // [128][128] bf16, n-major k-contig
    const float* __restrict__ bw,            // [128] f32
    const float* __restrict__ avec,          // [NN] f32
    const float* __restrict__ bmu, const float* __restrict__ bls,
    const float* __restrict__ init,
    float* __restrict__ outp) {
    __shared__ float rowbuf[4][132];         // 4 nodes x 128 f32 g2 rows
    int tid = threadIdx.x;
    int n4 = tid >> 6;
    int node = blockIdx.x * 4 + n4;
    int lane = tid & 63;
    int q = lane >> 4, l16 = lane & 15;
    int deg = __builtin_amdgcn_readfirstlane(cnt[node]);
    float dn = rsqrtf((float)(deg + 1));
    if (deg > SLOTS) deg = SLOTS;
    float a[8] = {0.f, 0.f, 0.f, 0.f, 0.f, 0.f, 0.f, 0.f};
    if (q == 0) {  // self term
        uint4 p = *(const uint4*)(tab + (size_t)node * 128 + l16 * 8);
        a[0] = bf2f(p.x & 0xffffu); a[1] = bf2f(p.x >> 16);
        a[2] = bf2f(p.y & 0xffffu); a[3] = bf2f(p.y >> 16);
        a[4] = bf2f(p.z & 0xffffu); a[5] = bf2f(p.z >> 16);
        a[6] = bf2f(p.w & 0xffffu); a[7] = bf2f(p.w >> 16);
    }
    int base = node * SLOTS;
    int t = q;
    while (t + 4 < deg) {
        int s0 = csr48[base + t];
        int s1 = csr48[base + t + 4];
        uint4 r0 = *(const uint4*)(tab + (size_t)s0 * 128 + l16 * 8);
        uint4 r1 = *(const uint4*)(tab + (size_t)s1 * 128 + l16 * 8);
        a[0] += bf2f(r0.x & 0xffffu) + bf2f(r1.x & 0xffffu);
        a[1] += bf2f(r0.x >> 16)     + bf2f(r1.x >> 16);
        a[2] += bf2f(r0.y & 0xffffu) + bf2f(r1.y & 0xffffu);
        a[3] += bf2f(r0.y >> 16)     + bf2f(r1.y >> 16);
        a[4] += bf2f(r0.z & 0xffffu) + bf2f(r1.z & 0xffffu);
        a[5] += bf2f(r0.z >> 16)     + bf2f(r1.z >> 16);
        a[6] += bf2f(r0.w & 0xffffu) + bf2f(r1.w & 0xffffu);
        a[7] += bf2f(r0.w >> 16)     + bf2f(r1.w >> 16);
        t += 8;
    }
    while (t < deg) {
        int s = csr48[base + t];
        uint4 r = *(const uint4*)(tab + (size_t)s * 128 + l16 * 8);
        a[0] += bf2f(r.x & 0xffffu); a[1] += bf2f(r.x >> 16);
        a[2] += bf2f(r.y & 0xffffu); a[3] += bf2f(r.y >> 16);
        a[4] += bf2f(r.z & 0xffffu); a[5] += bf2f(r.z >> 16);
        a[6] += bf2f(r.w & 0xffffu); a[7] += bf2f(r.w >> 16);
        t += 4;
    }
#pragma unroll
    for (int j = 0; j < 8; ++j) {
        a[j] += __shfl_xor(a[j], 16);
        a[j] += __shfl_xor(a[j], 32);
    }
    if (q == 0) {
        // keep g2 row in f32 (no bf16 roundtrip; >= accuracy of the split path)
#pragma unroll
        for (int j = 0; j < 8; ++j) rowbuf[n4][l16 * 8 + j] = a[j] * dn;
    }
    __syncthreads();
    // ---- fused VALU GEMM: thread -> (node n4, col cm); 2 dots of length 128 ----
    int cm = lane;                            // 0..63
    const float* row = rowbuf[n4];
    const unsigned short* wm = W2c + (size_t)cm * 128;
    const unsigned short* wl = W2c + (size_t)(cm + 64) * 128;
    float accm = 0.f, accl = 0.f;
#pragma unroll 16
    for (int k = 0; k < 128; ++k) {
        float rk = row[k];                    // LDS broadcast (same addr across node's lanes)
        accm += rk * bf2f(wm[k]);
        accl += rk * bf2f(wl[k]);
    }
    float av = avec[node];
    float mu = accm + av * bw[cm] + bmu[cm];
    float ls = accl + av * bw[cm + 64] + bls[cm];
    float idv = init[(size_t)node * 64 + cm];
    outp[(size_t)node * 64 + cm] = mu + idv * expf(ls);
}

extern "C" void kernel_launch(void* const* d_in, const int* in_sizes, int n_in,
                              void* d_out, int out_size, void* d_ws, size_t ws_size,
                              hipStream_t stream) {
    const float* x   = (const float*)d_in[0];  // [N,128] f32
    const int*   ei  = (const int*)d_in[1];    // [2,E] int32
    const float* ind = (const float*)d_in[2];  // [N,64] f32
    const float* W1  = (const float*)d_in[3];  // [128,128] f32
    const float* b1  = (const float*)d_in[4];  // [128] f32
    const float* Wmu = (const float*)d_in[5];  // [128,64] f32
    const float* bmu = (const float*)d_in[6];  // [64] f32
    const float* Wls = (const float*)d_in[7];  // [128,64] f32
    const float* bls = (const float*)d_in[8];  // [64] f32
    float* outp = (float*)d_out;               // [N,64] f32

    char* w = (char*)d_ws;
    auto carve = [&](size_t bytes) -> char* {
        char* p = w; w += (bytes + 255) & ~(size_t)255; return p;
    };
    int*   cnt  = (int*)carve((size_t)NN * 4);
    float* avec = (float*)carve((size_t)NN * 4);
    float* bw   = (float*)carve(128 * 4);
    unsigned short* W2c = (unsigned short*)carve(128 * 128 * 2);
    unsigned short* xs  = (unsigned short*)carve((size_t)NN * 128 * 2);  // xq
    unsigned short* t1  = (unsigned short*)carve((size_t)NN * 128 * 2);  // gather1 output
    int* csr = (int*)carve((size_t)NN * SLOTS * 4);
    // ~71.5 MB total — proven-fit layout

    hipMemsetAsync(cnt, 0, (size_t)NN * 4, stream);
    k_front<<<FRONT_B, 256, 0, stream>>>(ei, cnt, csr, x, xs, W1, Wmu, Wls, b1, W2c, bw);
    k_gather1<<<NN / 4, 256, 0, stream>>>(xs, cnt, csr, t1, avec);
    k_gather2C<<<NN / 4, 256, 0, stream>>>(t1, cnt, csr, W2c, bw, avec, bmu, bls, ind, outp);
}

// Round 10
// 346.470 us; speedup vs baseline: 1.8930x; 1.8930x over previous
//
#include <hip/hip_runtime.h>
#include <math.h>

#define NN 100000
#define NE 1600000
#define SLOTS 48           // fixed csr stride; P(deg>=48) ~ 6e-11 per node
#define NODES_PER_BUCKET 12500   // 8 buckets x 12500 = NN
#define QUADS (NE / 4)     // 400000
#define CSEG 128           // count-fill segments per bucket (1024 blocks total)
#define QPS2 ((QUADS + CSEG - 1) / CSEG)  // 3125
#define XCAST_T (NN * 32)            // 3,200,000 xcast threads
#define PREP_T (XCAST_T + 16384 + 128)
#define PREP_B ((PREP_T + 255) / 256)    // 12565
#define FRONT_B (1024 + PREP_B)

// bf16 <-> f32 helpers (bf16 stored as raw ushort; value<<16 == f32 bits)
__device__ __forceinline__ float bf2f(unsigned int u) {
    union { unsigned int u; float f; } c; c.u = u << 16; return c.f;
}
__device__ __forceinline__ unsigned short f2bf(float f) {
    union { float f; unsigned int u; } c; c.f = f;
    unsigned int x = c.u;
    return (unsigned short)((x + 0x7fffu + ((x >> 16) & 1u)) >> 16); // RNE
}

typedef __attribute__((ext_vector_type(8))) short short8;
typedef __attribute__((ext_vector_type(4))) float float4v;

// ---------- k_front: CSR build (1024 blocks, dispatched first) + indep prep ----------
// R8-proven: count portion is atomic-rate bound, 1024 blocks sustain it while the
// prep (xq = bf16(x), W2c = W1@[Wmu|Wls], bw = b1@[Wmu|Wls]) fills freed capacity.
__global__ __launch_bounds__(256) void k_front(const int* __restrict__ ei,
        int* __restrict__ cnt, int* __restrict__ csr48,
        const float* __restrict__ x, unsigned short* __restrict__ xq,
        const float* __restrict__ W1, const float* __restrict__ Wmu,
        const float* __restrict__ Wls, const float* __restrict__ b1,
        unsigned short* __restrict__ W2c, float* __restrict__ bw) {
    int b = blockIdx.x;
    if (b < 1024) {
        int bucket = b & 7;
        int seg = b >> 3;                // 0..127
        int lo = bucket * NODES_PER_BUCKET, hi = lo + NODES_PER_BUCKET;
        int q1 = min((seg + 1) * QPS2, QUADS);
        for (int q = seg * QPS2 + (int)threadIdx.x; q < q1; q += 256) {
            int e0 = q * 4;
            int4 s = *(const int4*)(ei + e0);
            int4 d = *(const int4*)(ei + NE + e0);
            int r;
            if (d.x >= lo && d.x < hi) { r = atomicAdd(&cnt[d.x], 1); if (r < SLOTS) csr48[d.x * SLOTS + r] = s.x; }
            if (d.y >= lo && d.y < hi) { r = atomicAdd(&cnt[d.y], 1); if (r < SLOTS) csr48[d.y * SLOTS + r] = s.y; }
            if (d.z >= lo && d.z < hi) { r = atomicAdd(&cnt[d.z], 1); if (r < SLOTS) csr48[d.z * SLOTS + r] = s.z; }
            if (d.w >= lo && d.w < hi) { r = atomicAdd(&cnt[d.w], 1); if (r < SLOTS) csr48[d.w * SLOTS + r] = s.w; }
        }
    } else {
        int idx = (b - 1024) * 256 + (int)threadIdx.x;
        if (idx < XCAST_T) {
            int node = idx >> 5, c = (idx & 31) << 2;
            float4 v = *(const float4*)(x + (size_t)node * 128 + c);
            uint2 st;
            st.x = ((unsigned int)f2bf(v.y) << 16) | f2bf(v.x);
            st.y = ((unsigned int)f2bf(v.w) << 16) | f2bf(v.z);
            *(uint2*)(xq + (size_t)node * 128 + c) = st;
        } else if (idx < XCAST_T + 16384) {
            int j = idx - XCAST_T;
            int k = j >> 7, n = j & 127;        // k = input feat (K dim), n = out col
            const float* Wx = (n < 64) ? (Wmu + n) : (Wls + (n - 64));  // col base, stride 64
            float s = 0.f;
#pragma unroll 8
            for (int m = 0; m < 128; ++m) s += W1[k * 128 + m] * Wx[(size_t)m * 64];
            W2c[n * 128 + k] = f2bf(s);
        } else if (idx < PREP_T) {
            int n = idx - XCAST_T - 16384;
            const float* Wx = (n < 64) ? (Wmu + n) : (Wls + (n - 64));
            float s = 0.f;
            for (int m = 0; m < 128; ++m) s += b1[m] * Wx[(size_t)m * 64];
            bw[n] = s;
        }
    }
}

// -------- gather1: t1 = bf16(dn^2 * (dn*x_n + sum_s d_s*xq_s)); avec = dn*(dn+sum d_s) --------
__global__ __launch_bounds__(256) void k_gather1(
    const unsigned short* __restrict__ tab, const int* __restrict__ cnt,
    const int* __restrict__ csr48,
    unsigned short* __restrict__ yout, float* __restrict__ avec) {
    int node = blockIdx.x * 4 + (threadIdx.x >> 6);   // NN % 4 == 0
    int lane = threadIdx.x & 63;
    int q = lane >> 4, l16 = lane & 15;
    int deg = __builtin_amdgcn_readfirstlane(cnt[node]);
    float dn = rsqrtf((float)(deg + 1));              // raw degree (+self)
    if (deg > SLOTS) deg = SLOTS;
    float a[8] = {0.f, 0.f, 0.f, 0.f, 0.f, 0.f, 0.f, 0.f};
    float asum = 0.f;
    if (q == 0) {  // self term, scaled by dn
        uint4 p = *(const uint4*)(tab + (size_t)node * 128 + l16 * 8);
        a[0] = dn * bf2f(p.x & 0xffffu); a[1] = dn * bf2f(p.x >> 16);
        a[2] = dn * bf2f(p.y & 0xffffu); a[3] = dn * bf2f(p.y >> 16);
        a[4] = dn * bf2f(p.z & 0xffffu); a[5] = dn * bf2f(p.z >> 16);
        a[6] = dn * bf2f(p.w & 0xffffu); a[7] = dn * bf2f(p.w >> 16);
    }
    int base = node * SLOTS;
    int t = q;
    while (t + 4 < deg) {   // 2 edges per quarter in flight (8/wave)
        int s0 = csr48[base + t];
        int s1 = csr48[base + t + 4];
        float d0 = rsqrtf((float)(cnt[s0] + 1));
        float d1 = rsqrtf((float)(cnt[s1] + 1));
        uint4 r0 = *(const uint4*)(tab + (size_t)s0 * 128 + l16 * 8);
        uint4 r1 = *(const uint4*)(tab + (size_t)s1 * 128 + l16 * 8);
        asum += d0 + d1;
        a[0] += d0 * bf2f(r0.x & 0xffffu) + d1 * bf2f(r1.x & 0xffffu);
        a[1] += d0 * bf2f(r0.x >> 16)     + d1 * bf2f(r1.x >> 16);
        a[2] += d0 * bf2f(r0.y & 0xffffu) + d1 * bf2f(r1.y & 0xffffu);
        a[3] += d0 * bf2f(r0.y >> 16)     + d1 * bf2f(r1.y >> 16);
        a[4] += d0 * bf2f(r0.z & 0xffffu) + d1 * bf2f(r1.z & 0xffffu);
        a[5] += d0 * bf2f(r0.z >> 16)     + d1 * bf2f(r1.z >> 16);
        a[6] += d0 * bf2f(r0.w & 0xffffu) + d1 * bf2f(r1.w & 0xffffu);
        a[7] += d0 * bf2f(r0.w >> 16)     + d1 * bf2f(r1.w >> 16);
        t += 8;
    }
    while (t < deg) {
        int s = csr48[base + t];
        float ds = rsqrtf((float)(cnt[s] + 1));
        uint4 r = *(const uint4*)(tab + (size_t)s * 128 + l16 * 8);
        asum += ds;
        a[0] += ds * bf2f(r.x & 0xffffu); a[1] += ds * bf2f(r.x >> 16);
        a[2] += ds * bf2f(r.y & 0xffffu); a[3] += ds * bf2f(r.y >> 16);
        a[4] += ds * bf2f(r.z & 0xffffu); a[5] += ds * bf2f(r.z >> 16);
        a[6] += ds * bf2f(r.w & 0xffffu); a[7] += ds * bf2f(r.w >> 16);
        t += 4;
    }
#pragma unroll
    for (int j = 0; j < 8; ++j) {
        a[j] += __shfl_xor(a[j], 16);
        a[j] += __shfl_xor(a[j], 32);
    }
    asum += __shfl_xor(asum, 16);
    asum += __shfl_xor(asum, 32);
    if (q == 0) {
        float d2 = dn * dn;      // t1 = dn * g1: pre-scales the gather2 source
        uint4 st;
        st.x = ((unsigned int)f2bf(a[1] * d2) << 16) | f2bf(a[0] * d2);
        st.y = ((unsigned int)f2bf(a[3] * d2) << 16) | f2bf(a[2] * d2);
        st.z = ((unsigned int)f2bf(a[5] * d2) << 16) | f2bf(a[4] * d2);
        st.w = ((unsigned int)f2bf(a[7] * d2) << 16) | f2bf(a[6] * d2);
        *(uint4*)(yout + (size_t)node * 128 + l16 * 8) = st;
        if (l16 == 0) avec[node] = dn * (asum + dn);   // a = G*1
    }
}

// ------- gather2M: 16 nodes/block (4/wave serial, R0-exact access pattern) into a
// 16x128 LDS A-tile, then the PROVEN gemmC MFMA body (coalesced short8 B-loads).
// 6250 blocks x 4 waves = 25000 waves = 3x the 8192-wave residency -> memory
// parallelism unchanged vs standalone gather (R9's VALU-dot and R4's starved-grid
// failure modes both avoided). Saves gemmC dispatch + gap + 51MB g2 roundtrip.
__global__ __launch_bounds__(256) void k_gather2M(
    const unsigned short* __restrict__ tab,  // t1 [NN][128] bf16 (pre-scaled by src dn)
    const int* __restrict__ cnt, const int* __restrict__ csr48,
    const unsigned short* __restrict__ Bt,   // W2c [128][128] bf16, n-major k-contig
    const float* __restrict__ bw,            // [128] f32
    const float* __restrict__ avec,          // [NN] f32
    const float* __restrict__ bmu, const float* __restrict__ bls,
    const float* __restrict__ init,
    float* __restrict__ outp) {
    __shared__ __align__(16) unsigned short As[16 * 136];
    int tid = threadIdx.x;
    int wave = tid >> 6;
    int lane = tid & 63;
    int q = lane >> 4, l16 = lane & 15;
    int r0 = blockIdx.x * 16;                 // NN/16 = 6250 exact
#pragma unroll 1
    for (int it = 0; it < 4; ++it) {
        int row = wave * 4 + it;
        int node = r0 + row;
        int deg = __builtin_amdgcn_readfirstlane(cnt[node]);
        float dn = rsqrtf((float)(deg + 1));
        if (deg > SLOTS) deg = SLOTS;
        float a[8] = {0.f, 0.f, 0.f, 0.f, 0.f, 0.f, 0.f, 0.f};
        if (q == 0) {  // self term
            uint4 p = *(const uint4*)(tab + (size_t)node * 128 + l16 * 8);
            a[0] = bf2f(p.x & 0xffffu); a[1] = bf2f(p.x >> 16);
            a[2] = bf2f(p.y & 0xffffu); a[3] = bf2f(p.y >> 16);
            a[4] = bf2f(p.z & 0xffffu); a[5] = bf2f(p.z >> 16);
            a[6] = bf2f(p.w & 0xffffu); a[7] = bf2f(p.w >> 16);
        }
        int base = node * SLOTS;
        int t = q;
        while (t + 4 < deg) {   // 2 edges per quarter in flight (8/wave)
            int s0 = csr48[base + t];
            int s1 = csr48[base + t + 4];
            uint4 rr0 = *(const uint4*)(tab + (size_t)s0 * 128 + l16 * 8);
            uint4 rr1 = *(const uint4*)(tab + (size_t)s1 * 128 + l16 * 8);
            a[0] += bf2f(rr0.x & 0xffffu) + bf2f(rr1.x & 0xffffu);
            a[1] += bf2f(rr0.x >> 16)     + bf2f(rr1.x >> 16);
            a[2] += bf2f(rr0.y & 0xffffu) + bf2f(rr1.y & 0xffffu);
            a[3] += bf2f(rr0.y >> 16)     + bf2f(rr1.y >> 16);
            a[4] += bf2f(rr0.z & 0xffffu) + bf2f(rr1.z & 0xffffu);
            a[5] += bf2f(rr0.z >> 16)     + bf2f(rr1.z >> 16);
            a[6] += bf2f(rr0.w & 0xffffu) + bf2f(rr1.w & 0xffffu);
            a[7] += bf2f(rr0.w >> 16)     + bf2f(rr1.w >> 16);
            t += 8;
        }
        while (t < deg) {
            int s = csr48[base + t];
            uint4 r = *(const uint4*)(tab + (size_t)s * 128 + l16 * 8);
            a[0] += bf2f(r.x & 0xffffu); a[1] += bf2f(r.x >> 16);
            a[2] += bf2f(r.y & 0xffffu); a[3] += bf2f(r.y >> 16);
            a[4] += bf2f(r.z & 0xffffu); a[5] += bf2f(r.z >> 16);
            a[6] += bf2f(r.w & 0xffffu); a[7] += bf2f(r.w >> 16);
            t += 4;
        }
#pragma unroll
        for (int j = 0; j < 8; ++j) {
            a[j] += __shfl_xor(a[j], 16);
            a[j] += __shfl_xor(a[j], 32);
        }
        if (q == 0) {  // bf16 row into A-tile (same values the split path stored)
            uint4 st;
            st.x = ((unsigned int)f2bf(a[1] * dn) << 16) | f2bf(a[0] * dn);
            st.y = ((unsigned int)f2bf(a[3] * dn) << 16) | f2bf(a[2] * dn);
            st.z = ((unsigned int)f2bf(a[5] * dn) << 16) | f2bf(a[4] * dn);
            st.w = ((unsigned int)f2bf(a[7] * dn) << 16) | f2bf(a[6] * dn);
            *(uint4*)(As + row * 136 + l16 * 8) = st;
        }
    }
    __syncthreads();
    // ---- gemmC MFMA body, rt=0 (16-row tile): wave -> mu col c0, ls col c1 ----
    int quad = lane >> 4;
    int cm = wave * 16 + l16;        // mu col (0..63)
    int cl = 64 + cm;                // matching ls col
    float4v accm = {0.f, 0.f, 0.f, 0.f};
    float4v accl = {0.f, 0.f, 0.f, 0.f};
#pragma unroll
    for (int ks = 0; ks < 4; ++ks) {
        short8 b0 = *(const short8*)(Bt + (size_t)cm * 128 + ks * 32 + quad * 8);
        short8 b1 = *(const short8*)(Bt + (size_t)cl * 128 + ks * 32 + quad * 8);
        short8 af = *(const short8*)(As + l16 * 136 + ks * 32 + quad * 8);
        accm = __builtin_amdgcn_mfma_f32_16x16x32_bf16(af, b0, accm, 0, 0, 0);
        accl = __builtin_amdgcn_mfma_f32_16x16x32_bf16(af, b1, accl, 0, 0, 0);
    }
    float bc_mu = bmu[cm], bc_ls = bls[cm];
    float bwm = bw[cm], bwl = bw[cl];
#pragma unroll
    for (int reg = 0; reg < 4; ++reg) {
        int gr = r0 + quad * 4 + reg;
        float av = avec[gr];
        float mu = accm[reg] + av * bwm + bc_mu;
        float ls = accl[reg] + av * bwl + bc_ls;
        float idv = init[(size_t)gr * 64 + cm];
        outp[(size_t)gr * 64 + cm] = mu + idv * expf(ls);
    }
}

extern "C" void kernel_launch(void* const* d_in, const int* in_sizes, int n_in,
                              void* d_out, int out_size, void* d_ws, size_t ws_size,
                              hipStream_t stream) {
    const float* x   = (const float*)d_in[0];  // [N,128] f32
    const int*   ei  = (const int*)d_in[1];    // [2,E] int32
    const float* ind = (const float*)d_in[2];  // [N,64] f32
    const float* W1  = (const float*)d_in[3];  // [128,128] f32
    const float* b1  = (const float*)d_in[4];  // [128] f32
    const float* Wmu = (const float*)d_in[5];  // [128,64] f32
    const float* bmu = (const float*)d_in[6];  // [64] f32
    const float* Wls = (const float*)d_in[7];  // [128,64] f32
    const float* bls = (const float*)d_in[8];  // [64] f32
    float* outp = (float*)d_out;               // [N,64] f32

    char* w = (char*)d_ws;
    auto carve = [&](size_t bytes) -> char* {
        char* p = w; w += (bytes + 255) & ~(size_t)255; return p;
    };
    int*   cnt  = (int*)carve((size_t)NN * 4);
    float* avec = (float*)carve((size_t)NN * 4);
    float* bw   = (float*)carve(128 * 4);
    unsigned short* W2c = (unsigned short*)carve(128 * 128 * 2);
    unsigned short* xs  = (unsigned short*)carve((size_t)NN * 128 * 2);  // xq
    unsigned short* t1  = (unsigned short*)carve((size_t)NN * 128 * 2);  // gather1 output
    int* csr = (int*)carve((size_t)NN * SLOTS * 4);
    // ~71.5 MB total — proven-fit layout

    hipMemsetAsync(cnt, 0, (size_t)NN * 4, stream);
    k_front<<<FRONT_B, 256, 0, stream>>>(ei, cnt, csr, x, xs, W1, Wmu, Wls, b1, W2c, bw);
    k_gather1<<<NN / 4, 256, 0, stream>>>(xs, cnt, csr, t1, avec);
    k_gather2M<<<NN / 16, 256, 0, stream>>>(t1, cnt, csr, W2c, bw, avec, bmu, bls, ind, outp);
}

// Round 11
// 343.927 us; speedup vs baseline: 1.9070x; 1.0074x over previous
//
#include <hip/hip_runtime.h>
#include <math.h>

#define NN 100000
#define NE 1600000
#define SLOTS 48           // fixed csr stride; P(deg>=48) ~ 6e-11 per node
#define NODES_PER_BUCKET 12500   // 8 buckets x 12500 = NN
#define QUADS (NE / 4)     // 400000
#define CSEG 192           // count segments per bucket -> 1536 count blocks (R11: was 128/1024)
#define QPS2 ((QUADS + CSEG - 1) / CSEG)  // 2084
#define CBLK (8 * CSEG)    // 1536
#define XCAST_T (NN * 32)            // 3,200,000 xcast threads
#define PREP_T (XCAST_T + 16384 + 128)
#define PREP_B ((PREP_T + 255) / 256)    // 12565
#define FRONT_B (CBLK + PREP_B)

// bf16 <-> f32 helpers (bf16 stored as raw ushort; value<<16 == f32 bits)
__device__ __forceinline__ float bf2f(unsigned int u) {
    union { unsigned int u; float f; } c; c.u = u << 16; return c.f;
}
__device__ __forceinline__ unsigned short f2bf(float f) {
    union { float f; unsigned int u; } c; c.f = f;
    unsigned int x = c.u;
    return (unsigned short)((x + 0x7fffu + ((x >> 16) & 1u)) >> 16); // RNE
}

typedef __attribute__((ext_vector_type(8))) short short8;
typedef __attribute__((ext_vector_type(4))) float float4v;

// ---------- k_front: CSR build (1536 blocks, dispatched first) + indep prep ----------
// Count is atomic-service bound: 77us@2048blk, ~85-89us@1024blk. 1536 blocks should
// recover most of the rate; prep (~18us machine-time: xq cast, W2c = W1@[Wmu|Wls],
// bw = b1@[Wmu|Wls]) fills the remaining ~25% residency and stays off the critical path.
__global__ __launch_bounds__(256) void k_front(const int* __restrict__ ei,
        int* __restrict__ cnt, int* __restrict__ csr48,
        const float* __restrict__ x, unsigned short* __restrict__ xq,
        const float* __restrict__ W1, const float* __restrict__ Wmu,
        const float* __restrict__ Wls, const float* __restrict__ b1,
        unsigned short* __restrict__ W2c, float* __restrict__ bw) {
    int b = blockIdx.x;
    if (b < CBLK) {
        int bucket = b & 7;
        int seg = b >> 3;                // 0..CSEG-1
        int lo = bucket * NODES_PER_BUCKET, hi = lo + NODES_PER_BUCKET;
        int q1 = min((seg + 1) * QPS2, QUADS);
        for (int q = seg * QPS2 + (int)threadIdx.x; q < q1; q += 256) {
            int e0 = q * 4;
            int4 s = *(const int4*)(ei + e0);
            int4 d = *(const int4*)(ei + NE + e0);
            int r;
            if (d.x >= lo && d.x < hi) { r = atomicAdd(&cnt[d.x], 1); if (r < SLOTS) csr48[d.x * SLOTS + r] = s.x; }
            if (d.y >= lo && d.y < hi) { r = atomicAdd(&cnt[d.y], 1); if (r < SLOTS) csr48[d.y * SLOTS + r] = s.y; }
            if (d.z >= lo && d.z < hi) { r = atomicAdd(&cnt[d.z], 1); if (r < SLOTS) csr48[d.z * SLOTS + r] = s.z; }
            if (d.w >= lo && d.w < hi) { r = atomicAdd(&cnt[d.w], 1); if (r < SLOTS) csr48[d.w * SLOTS + r] = s.w; }
        }
    } else {
        int idx = (b - CBLK) * 256 + (int)threadIdx.x;
        if (idx < XCAST_T) {
            int node = idx >> 5, c = (idx & 31) << 2;
            float4 v = *(const float4*)(x + (size_t)node * 128 + c);
            uint2 st;
            st.x = ((unsigned int)f2bf(v.y) << 16) | f2bf(v.x);
            st.y = ((unsigned int)f2bf(v.w) << 16) | f2bf(v.z);
            *(uint2*)(xq + (size_t)node * 128 + c) = st;
        } else if (idx < XCAST_T + 16384) {
            int j = idx - XCAST_T;
            int k = j >> 7, n = j & 127;        // k = input feat (K dim), n = out col
            const float* Wx = (n < 64) ? (Wmu + n) : (Wls + (n - 64));  // col base, stride 64
            float s = 0.f;
#pragma unroll 8
            for (int m = 0; m < 128; ++m) s += W1[k * 128 + m] * Wx[(size_t)m * 64];
            W2c[n * 128 + k] = f2bf(s);
        } else if (idx < PREP_T) {
            int n = idx - XCAST_T - 16384;
            const float* Wx = (n < 64) ? (Wmu + n) : (Wls + (n - 64));
            float s = 0.f;
            for (int m = 0; m < 128; ++m) s += b1[m] * Wx[(size_t)m * 64];
            bw[n] = s;
        }
    }
}

// -------- gather1: t1 = bf16(dn^2 * (dn*x_n + sum_s d_s*xq_s)); avec = dn*(dn+sum d_s) --------
__global__ __launch_bounds__(256) void k_gather1(
    const unsigned short* __restrict__ tab, const int* __restrict__ cnt,
    const int* __restrict__ csr48,
    unsigned short* __restrict__ yout, float* __restrict__ avec) {
    int node = blockIdx.x * 4 + (threadIdx.x >> 6);   // NN % 4 == 0
    int lane = threadIdx.x & 63;
    int q = lane >> 4, l16 = lane & 15;
    int deg = __builtin_amdgcn_readfirstlane(cnt[node]);
    float dn = rsqrtf((float)(deg + 1));              // raw degree (+self)
    if (deg > SLOTS) deg = SLOTS;
    float a[8] = {0.f, 0.f, 0.f, 0.f, 0.f, 0.f, 0.f, 0.f};
    float asum = 0.f;
    if (q == 0) {  // self term, scaled by dn
        uint4 p = *(const uint4*)(tab + (size_t)node * 128 + l16 * 8);
        a[0] = dn * bf2f(p.x & 0xffffu); a[1] = dn * bf2f(p.x >> 16);
        a[2] = dn * bf2f(p.y & 0xffffu); a[3] = dn * bf2f(p.y >> 16);
        a[4] = dn * bf2f(p.z & 0xffffu); a[5] = dn * bf2f(p.z >> 16);
        a[6] = dn * bf2f(p.w & 0xffffu); a[7] = dn * bf2f(p.w >> 16);
    }
    int base = node * SLOTS;
    int t = q;
    while (t + 4 < deg) {   // 2 edges per quarter in flight (8/wave)
        int s0 = csr48[base + t];
        int s1 = csr48[base + t + 4];
        float d0 = rsqrtf((float)(cnt[s0] + 1));
        float d1 = rsqrtf((float)(cnt[s1] + 1));
        uint4 r0 = *(const uint4*)(tab + (size_t)s0 * 128 + l16 * 8);
        uint4 r1 = *(const uint4*)(tab + (size_t)s1 * 128 + l16 * 8);
        asum += d0 + d1;
        a[0] += d0 * bf2f(r0.x & 0xffffu) + d1 * bf2f(r1.x & 0xffffu);
        a[1] += d0 * bf2f(r0.x >> 16)     + d1 * bf2f(r1.x >> 16);
        a[2] += d0 * bf2f(r0.y & 0xffffu) + d1 * bf2f(r1.y & 0xffffu);
        a[3] += d0 * bf2f(r0.y >> 16)     + d1 * bf2f(r1.y >> 16);
        a[4] += d0 * bf2f(r0.z & 0xffffu) + d1 * bf2f(r1.z & 0xffffu);
        a[5] += d0 * bf2f(r0.z >> 16)     + d1 * bf2f(r1.z >> 16);
        a[6] += d0 * bf2f(r0.w & 0xffffu) + d1 * bf2f(r1.w & 0xffffu);
        a[7] += d0 * bf2f(r0.w >> 16)     + d1 * bf2f(r1.w >> 16);
        t += 8;
    }
    while (t < deg) {
        int s = csr48[base + t];
        float ds = rsqrtf((float)(cnt[s] + 1));
        uint4 r = *(const uint4*)(tab + (size_t)s * 128 + l16 * 8);
        asum += ds;
        a[0] += ds * bf2f(r.x & 0xffffu); a[1] += ds * bf2f(r.x >> 16);
        a[2] += ds * bf2f(r.y & 0xffffu); a[3] += ds * bf2f(r.y >> 16);
        a[4] += ds * bf2f(r.z & 0xffffu); a[5] += ds * bf2f(r.z >> 16);
        a[6] += ds * bf2f(r.w & 0xffffu); a[7] += ds * bf2f(r.w >> 16);
        t += 4;
    }
#pragma unroll
    for (int j = 0; j < 8; ++j) {
        a[j] += __shfl_xor(a[j], 16);
        a[j] += __shfl_xor(a[j], 32);
    }
    asum += __shfl_xor(asum, 16);
    asum += __shfl_xor(asum, 32);
    if (q == 0) {
        float d2 = dn * dn;      // t1 = dn * g1: pre-scales the gather2 source
        uint4 st;
        st.x = ((unsigned int)f2bf(a[1] * d2) << 16) | f2bf(a[0] * d2);
        st.y = ((unsigned int)f2bf(a[3] * d2) << 16) | f2bf(a[2] * d2);
        st.z = ((unsigned int)f2bf(a[5] * d2) << 16) | f2bf(a[4] * d2);
        st.w = ((unsigned int)f2bf(a[7] * d2) << 16) | f2bf(a[6] * d2);
        *(uint4*)(yout + (size_t)node * 128 + l16 * 8) = st;
        if (l16 == 0) avec[node] = dn * (asum + dn);   // a = G*1
    }
}

// ------- gather2M: 16 nodes/block (4/wave serial, R0-exact access pattern) into a
// 16x128 LDS A-tile, then the PROVEN gemmC MFMA body (coalesced short8 B-loads).
// 6250 blocks x 4 waves = 25000 waves = 3x residency -> gather parallelism intact.
__global__ __launch_bounds__(256) void k_gather2M(
    const unsigned short* __restrict__ tab,  // t1 [NN][128] bf16 (pre-scaled by src dn)
    const int* __restrict__ cnt, const int* __restrict__ csr48,
    const unsigned short* __restrict__ Bt,   // W2c [128][128] bf16, n-major k-contig
    const float* __restrict__ bw,            // [128] f32
    const float* __restrict__ avec,          // [NN] f32
    const float* __restrict__ bmu, const float* __restrict__ bls,
    const float* __restrict__ init,
    float* __restrict__ outp) {
    __shared__ __align__(16) unsigned short As[16 * 136];
    int tid = threadIdx.x;
    int wave = tid >> 6;
    int lane = tid & 63;
    int q = lane >> 4, l16 = lane & 15;
    int r0 = blockIdx.x * 16;                 // NN/16 = 6250 exact
#pragma unroll 1
    for (int it = 0; it < 4; ++it) {
        int row = wave * 4 + it;
        int node = r0 + row;
        int deg = __builtin_amdgcn_readfirstlane(cnt[node]);
        float dn = rsqrtf((float)(deg + 1));
        if (deg > SLOTS) deg = SLOTS;
        float a[8] = {0.f, 0.f, 0.f, 0.f, 0.f, 0.f, 0.f, 0.f};
        if (q == 0) {  // self term
            uint4 p = *(const uint4*)(tab + (size_t)node * 128 + l16 * 8);
            a[0] = bf2f(p.x & 0xffffu); a[1] = bf2f(p.x >> 16);
            a[2] = bf2f(p.y & 0xffffu); a[3] = bf2f(p.y >> 16);
            a[4] = bf2f(p.z & 0xffffu); a[5] = bf2f(p.z >> 16);
            a[6] = bf2f(p.w & 0xffffu); a[7] = bf2f(p.w >> 16);
        }
        int base = node * SLOTS;
        int t = q;
        while (t + 4 < deg) {   // 2 edges per quarter in flight (8/wave)
            int s0 = csr48[base + t];
            int s1 = csr48[base + t + 4];
            uint4 rr0 = *(const uint4*)(tab + (size_t)s0 * 128 + l16 * 8);
            uint4 rr1 = *(const uint4*)(tab + (size_t)s1 * 128 + l16 * 8);
            a[0] += bf2f(rr0.x & 0xffffu) + bf2f(rr1.x & 0xffffu);
            a[1] += bf2f(rr0.x >> 16)     + bf2f(rr1.x >> 16);
            a[2] += bf2f(rr0.y & 0xffffu) + bf2f(rr1.y & 0xffffu);
            a[3] += bf2f(rr0.y >> 16)     + bf2f(rr1.y >> 16);
            a[4] += bf2f(rr0.z & 0xffffu) + bf2f(rr1.z & 0xffffu);
            a[5] += bf2f(rr0.z >> 16)     + bf2f(rr1.z >> 16);
            a[6] += bf2f(rr0.w & 0xffffu) + bf2f(rr1.w & 0xffffu);
            a[7] += bf2f(rr0.w >> 16)     + bf2f(rr1.w >> 16);
            t += 8;
        }
        while (t < deg) {
            int s = csr48[base + t];
            uint4 r = *(const uint4*)(tab + (size_t)s * 128 + l16 * 8);
            a[0] += bf2f(r.x & 0xffffu); a[1] += bf2f(r.x >> 16);
            a[2] += bf2f(r.y & 0xffffu); a[3] += bf2f(r.y >> 16);
            a[4] += bf2f(r.z & 0xffffu); a[5] += bf2f(r.z >> 16);
            a[6] += bf2f(r.w & 0xffffu); a[7] += bf2f(r.w >> 16);
            t += 4;
        }
#pragma unroll
        for (int j = 0; j < 8; ++j) {
            a[j] += __shfl_xor(a[j], 16);
            a[j] += __shfl_xor(a[j], 32);
        }
        if (q == 0) {  // bf16 row into A-tile (same values the split path stored)
            uint4 st;
            st.x = ((unsigned int)f2bf(a[1] * dn) << 16) | f2bf(a[0] * dn);
            st.y = ((unsigned int)f2bf(a[3] * dn) << 16) | f2bf(a[2] * dn);
            st.z = ((unsigned int)f2bf(a[5] * dn) << 16) | f2bf(a[4] * dn);
            st.w = ((unsigned int)f2bf(a[7] * dn) << 16) | f2bf(a[6] * dn);
            *(uint4*)(As + row * 136 + l16 * 8) = st;
        }
    }
    __syncthreads();
    // ---- gemmC MFMA body, rt=0 (16-row tile): wave -> mu col cm, ls col cl ----
    int quad = lane >> 4;
    int cm = wave * 16 + l16;        // mu col (0..63)
    int cl = 64 + cm;                // matching ls col
    float4v accm = {0.f, 0.f, 0.f, 0.f};
    float4v accl = {0.f, 0.f, 0.f, 0.f};
#pragma unroll
    for (int ks = 0; ks < 4; ++ks) {
        short8 b0 = *(const short8*)(Bt + (size_t)cm * 128 + ks * 32 + quad * 8);
        short8 b1 = *(const short8*)(Bt + (size_t)cl * 128 + ks * 32 + quad * 8);
        short8 af = *(const short8*)(As + l16 * 136 + ks * 32 + quad * 8);
        accm = __builtin_amdgcn_mfma_f32_16x16x32_bf16(af, b0, accm, 0, 0, 0);
        accl = __builtin_amdgcn_mfma_f32_16x16x32_bf16(af, b1, accl, 0, 0, 0);
    }
    float bc_mu = bmu[cm], bc_ls = bls[cm];
    float bwm = bw[cm], bwl = bw[cl];
#pragma unroll
    for (int reg = 0; reg < 4; ++reg) {
        int gr = r0 + quad * 4 + reg;
        float av = avec[gr];
        float mu = accm[reg] + av * bwm + bc_mu;
        float ls = accl[reg] + av * bwl + bc_ls;
        float idv = init[(size_t)gr * 64 + cm];
        outp[(size_t)gr * 64 + cm] = mu + idv * expf(ls);
    }
}

extern "C" void kernel_launch(void* const* d_in, const int* in_sizes, int n_in,
                              void* d_out, int out_size, void* d_ws, size_t ws_size,
                              hipStream_t stream) {
    const float* x   = (const float*)d_in[0];  // [N,128] f32
    const int*   ei  = (const int*)d_in[1];    // [2,E] int32
    const float* ind = (const float*)d_in[2];  // [N,64] f32
    const float* W1  = (const float*)d_in[3];  // [128,128] f32
    const float* b1  = (const float*)d_in[4];  // [128] f32
    const float* Wmu = (const float*)d_in[5];  // [128,64] f32
    const float* bmu = (const float*)d_in[6];  // [64] f32
    const float* Wls = (const float*)d_in[7];  // [128,64] f32
    const float* bls = (const float*)d_in[8];  // [64] f32
    float* outp = (float*)d_out;               // [N,64] f32

    char* w = (char*)d_ws;
    auto carve = [&](size_t bytes) -> char* {
        char* p = w; w += (bytes + 255) & ~(size_t)255; return p;
    };
    int*   cnt  = (int*)carve((size_t)NN * 4);
    float* avec = (float*)carve((size_t)NN * 4);
    float* bw   = (float*)carve(128 * 4);
    unsigned short* W2c = (unsigned short*)carve(128 * 128 * 2);
    unsigned short* xs  = (unsigned short*)carve((size_t)NN * 128 * 2);  // xq
    unsigned short* t1  = (unsigned short*)carve((size_t)NN * 128 * 2);  // gather1 output
    int* csr = (int*)carve((size_t)NN * SLOTS * 4);
    // ~71.5 MB total — proven-fit layout

    hipMemsetAsync(cnt, 0, (size_t)NN * 4, stream);
    k_front<<<FRONT_B, 256, 0, stream>>>(ei, cnt, csr, x, xs, W1, Wmu, Wls, b1, W2c, bw);
    k_gather1<<<NN / 4, 256, 0, stream>>>(xs, cnt, csr, t1, avec);
    k_gather2M<<<NN / 16, 256, 0, stream>>>(t1, cnt, csr, W2c, bw, avec, bmu, bls, ind, outp);
}